// Round 17
// baseline (51.065 us; speedup 1.0000x reference)
//
#include <hip/hip_runtime.h>
#include <hip/hip_bf16.h>
#include <math.h>

#define N_TOK 32768
#define DDIM 1024
#define NEXP 16
#define THREADS 256
#define TOK_PER_WAVE 16
#define TOK_PER_BLK 64
#define NBLK (N_TOK / TOK_PER_BLK)   // 512
#define KSTEPS (DDIM / 32)           // 32

typedef __attribute__((ext_vector_type(8))) short bf16x8;
typedef __attribute__((ext_vector_type(4))) float f32x4;

__device__ inline short f2bf(float f) {            // RNE f32->bf16 via HW cvt
    __hip_bfloat16 h = __float2bfloat16(f);
    return __builtin_bit_cast(short, h);
}

// Wfrag[s][tile][lane][j] (bf16): A-fragment stream for mfma_f32_16x16x32_bf16.
// row m = tile*16 + (lane&15)  (tile0 = Wg e0-15, tile1 = Wn e0-15)
// k     = s*32 + (lane>>4)*8 + j
__global__ __launch_bounds__(256) void make_wfrag(
    const float* __restrict__ Wg, const float* __restrict__ Wn,
    unsigned short* __restrict__ Wfrag)
{
    const int i    = blockIdx.x * 256 + threadIdx.x;   // 32768 total
    const int j    = i & 7;
    const int lane = (i >> 3) & 63;
    const int tile = (i >> 9) & 1;
    const int s    = i >> 10;
    const int k    = s * 32 + (lane >> 4) * 8 + j;
    const float* W = tile ? Wn : Wg;
    Wfrag[i] = (unsigned short)f2bf(W[(size_t)(lane & 15) * DDIM + k]);
}

// out layout (floats): [0,65536) top2 gates, [65536,131072) top2 indices (as float),
// [131072,131088) load
__global__ __launch_bounds__(THREADS) void router_mfma(
    const float* __restrict__ x, const float* __restrict__ noise,
    const unsigned short* __restrict__ Wfrag,
    float* __restrict__ out_gates, float* __restrict__ out_idx,
    float* __restrict__ partials)
{
    __shared__ float blk_load[NEXP];
    const int tid  = threadIdx.x;
    const int lane = tid & 63;
    const int w    = tid >> 6;
    if (tid < NEXP) blk_load[tid] = 0.0f;
    __syncthreads();

    const int tok = blockIdx.x * TOK_PER_BLK + w * TOK_PER_WAVE + (lane & 15);
    const int grp = lane >> 4;                       // 4-lane group id for this token

    const f32x4*          xb = (const f32x4*)(x + (size_t)tok * DDIM + grp * 8);
    const unsigned short* wb = Wfrag + (size_t)lane * 8;

    f32x4 acc0 = {0.f, 0.f, 0.f, 0.f};              // D rows 0-15  (gate logits)
    f32x4 acc1 = {0.f, 0.f, 0.f, 0.f};              // D rows 16-31 (noise logits)

#pragma unroll 8
    for (int s = 0; s < KSTEPS; ++s) {
        // non-temporal: x is stream-once; bypass L2/LLC allocation
        const f32x4 lo = __builtin_nontemporal_load(xb + s * 8);
        const f32x4 hi = __builtin_nontemporal_load(xb + s * 8 + 1);
        const bf16x8 a0 = *(const bf16x8*)(wb + (size_t)(s * 2 + 0) * 512);
        const bf16x8 a1 = *(const bf16x8*)(wb + (size_t)(s * 2 + 1) * 512);
        bf16x8 b;
        b[0] = f2bf(lo[0]); b[1] = f2bf(lo[1]); b[2] = f2bf(lo[2]); b[3] = f2bf(lo[3]);
        b[4] = f2bf(hi[0]); b[5] = f2bf(hi[1]); b[6] = f2bf(hi[2]); b[7] = f2bf(hi[3]);
        acc0 = __builtin_amdgcn_mfma_f32_16x16x32_bf16(a0, b, acc0, 0, 0, 0);
        acc1 = __builtin_amdgcn_mfma_f32_16x16x32_bf16(a1, b, acc1, 0, 0, 0);
    }

    // ---- epilogue: lane holds experts e = grp*4 + r for token tok ----
    const float4 nz4 = *(const float4*)(noise + (size_t)tok * NEXP + grp * 4);
    const float nzv[4] = {nz4.x, nz4.y, nz4.z, nz4.w};

    float lg[4];
#pragma unroll
    for (int r = 0; r < 4; ++r) {
        const float cl = acc0[r];
        const float nl = acc1[r];
        const float sp = fmaxf(nl, 0.0f) + log1pf(expf(-fabsf(nl)));
        lg[r] = cl + nzv[r] * sp * 0.01f;
    }

    float m = fmaxf(fmaxf(lg[0], lg[1]), fmaxf(lg[2], lg[3]));
    m = fmaxf(m, __shfl_xor(m, 16, 64));
    m = fmaxf(m, __shfl_xor(m, 32, 64));

    float p[4];
    float ssum = 0.0f;
#pragma unroll
    for (int r = 0; r < 4; ++r) { p[r] = expf(lg[r] - m); ssum += p[r]; }
    ssum += __shfl_xor(ssum, 16, 64);
    ssum += __shfl_xor(ssum, 32, 64);
    const float inv = 1.0f / ssum;

    float g[4];
#pragma unroll
    for (int r = 0; r < 4; ++r) g[r] = p[r] * inv;

    // local top-2 (tie -> lower index), butterfly merge across the 4 lanes
    float v1 = -1.0f, v2 = -1.0f;
    int   i1 = 0,     i2 = 0;
#pragma unroll
    for (int r = 0; r < 4; ++r) {
        const float ge = g[r];
        const int   e  = grp * 4 + r;
        if (ge > v1)      { v2 = v1; i2 = i1; v1 = ge; i1 = e; }
        else if (ge > v2) { v2 = ge; i2 = e; }
    }
#pragma unroll
    for (int off = 16; off <= 32; off <<= 1) {
        const float ov1 = __shfl_xor(v1, off, 64);
        const float ov2 = __shfl_xor(v2, off, 64);
        const int   oi1 = __shfl_xor(i1, off, 64);
        const int   oi2 = __shfl_xor(i2, off, 64);
        const bool aWins = (v1 > ov1) || (v1 == ov1 && i1 < oi1);
        float nv1, nv2; int ni1, ni2;
        if (aWins) {
            nv1 = v1; ni1 = i1;
            const bool bNext = (ov1 > v2) || (ov1 == v2 && oi1 < i2);
            nv2 = bNext ? ov1 : v2;  ni2 = bNext ? oi1 : i2;
        } else {
            nv1 = ov1; ni1 = oi1;
            const bool aNext = (v1 > ov2) || (v1 == ov2 && i1 < oi2);
            nv2 = aNext ? v1 : ov2;  ni2 = aNext ? i1 : oi2;
        }
        v1 = nv1; v2 = nv2; i1 = ni1; i2 = ni2;
    }
    if (grp == 0) {
        const float den = v1 + v2 + 1e-8f;
        out_gates[(size_t)tok * 2 + 0] = v1 / den;
        out_gates[(size_t)tok * 2 + 1] = v2 / den;
        out_idx[(size_t)tok * 2 + 0] = (float)i1;
        out_idx[(size_t)tok * 2 + 1] = (float)i2;
    }

    // load partials: sum g over the 16 tokens of this wave (butterfly over lane&15)
#pragma unroll
    for (int r = 0; r < 4; ++r) {
        float v = g[r];
        v += __shfl_xor(v, 1, 64);
        v += __shfl_xor(v, 2, 64);
        v += __shfl_xor(v, 4, 64);
        v += __shfl_xor(v, 8, 64);
        if ((lane & 15) == 0) atomicAdd(&blk_load[grp * 4 + r], v);
    }
    __syncthreads();
    if (tid < NEXP) partials[(size_t)blockIdx.x * NEXP + tid] = blk_load[tid];
}

__global__ __launch_bounds__(64) void reduce_load(
    const float* __restrict__ partials, float* __restrict__ out_load)
{
    const int lane = threadIdx.x;
    float loc[16];
#pragma unroll
    for (int e = 0; e < 16; ++e) loc[e] = 0.0f;
    for (int b = lane; b < NBLK; b += 64) {
        const float4* p = (const float4*)(partials + (size_t)b * 16);
#pragma unroll
        for (int j = 0; j < 4; ++j) {
            const float4 v = p[j];
            loc[j * 4 + 0] += v.x; loc[j * 4 + 1] += v.y;
            loc[j * 4 + 2] += v.z; loc[j * 4 + 3] += v.w;
        }
    }
#pragma unroll
    for (int e = 0; e < 16; ++e) {
        float v = loc[e];
#pragma unroll
        for (int off = 32; off; off >>= 1) v += __shfl_xor(v, off, 64);
        if (lane == 0) out_load[e] = v;
    }
}

extern "C" void kernel_launch(void* const* d_in, const int* in_sizes, int n_in,
                              void* d_out, int out_size, void* d_ws, size_t ws_size,
                              hipStream_t stream) {
    (void)in_sizes; (void)n_in; (void)ws_size; (void)out_size;
    const float* x     = (const float*)d_in[0];
    const float* noise = (const float*)d_in[1];
    const float* Wg    = (const float*)d_in[2];
    const float* Wn    = (const float*)d_in[3];

    float* out       = (float*)d_out;
    float* out_gates = out;
    float* out_idx   = out + (size_t)N_TOK * 2;
    float* out_load  = out + (size_t)N_TOK * 4;

    unsigned short* Wfrag = (unsigned short*)d_ws;                 // 64 KB
    float* partials = (float*)((char*)d_ws + 65536);               // NBLK*16 floats

    make_wfrag<<<128, 256, 0, stream>>>(Wg, Wn, Wfrag);            // 32768 elems
    router_mfma<<<NBLK, THREADS, 0, stream>>>(
        x, noise, Wfrag, out_gates, out_idx, partials);
    reduce_load<<<1, 64, 0, stream>>>(partials, out_load);
}

// Round 18
// 39.187 us; speedup vs baseline: 1.3031x; 1.3031x over previous
//
#include <hip/hip_runtime.h>
#include <hip/hip_bf16.h>
#include <math.h>

#define N_TOK 32768
#define DDIM 1024
#define NEXP 16
#define THREADS 256
#define TOK_PER_WAVE 16
#define TOK_PER_BLK 64
#define NBLK (N_TOK / TOK_PER_BLK)   // 512
#define KSTEPS (DDIM / 32)           // 32

typedef __attribute__((ext_vector_type(8))) short bf16x8;
typedef __attribute__((ext_vector_type(4))) float f32x4;

__device__ inline short f2bf(float f) {            // RNE f32->bf16 via HW cvt
    __hip_bfloat16 h = __float2bfloat16(f);
    return __builtin_bit_cast(short, h);
}

// Wfrag[s][tile][lane][j] (bf16): A-fragment stream for mfma_f32_16x16x32_bf16.
// row m = tile*16 + (lane&15)  (tile0 = Wg e0-15, tile1 = Wn e0-15)
// k     = s*32 + (lane>>4)*8 + j
__global__ __launch_bounds__(256) void make_wfrag(
    const float* __restrict__ Wg, const float* __restrict__ Wn,
    unsigned short* __restrict__ Wfrag)
{
    const int i    = blockIdx.x * 256 + threadIdx.x;   // 32768 total
    const int j    = i & 7;
    const int lane = (i >> 3) & 63;
    const int tile = (i >> 9) & 1;
    const int s    = i >> 10;
    const int k    = s * 32 + (lane >> 4) * 8 + j;
    const float* W = tile ? Wn : Wg;
    Wfrag[i] = (unsigned short)f2bf(W[(size_t)(lane & 15) * DDIM + k]);
}

// out layout (floats): [0,65536) top2 gates, [65536,131072) top2 indices (as float),
// [131072,131088) load
__global__ __launch_bounds__(THREADS, 1) void router_mfma(   // 1 wave/EU min: free VGPRs for deep pipeline
    const float* __restrict__ x, const float* __restrict__ noise,
    const unsigned short* __restrict__ Wfrag,
    float* __restrict__ out_gates, float* __restrict__ out_idx,
    float* __restrict__ partials)
{
    __shared__ float blk_load[NEXP];
    const int tid  = threadIdx.x;
    const int lane = tid & 63;
    const int w    = tid >> 6;
    if (tid < NEXP) blk_load[tid] = 0.0f;
    __syncthreads();

    const int tok = blockIdx.x * TOK_PER_BLK + w * TOK_PER_WAVE + (lane & 15);
    const int grp = lane >> 4;                       // 4-lane group id for this token

    const float*          xb = x + (size_t)tok * DDIM + grp * 8;
    const unsigned short* wb = Wfrag + (size_t)lane * 8;

    f32x4 acc0 = {0.f, 0.f, 0.f, 0.f};              // D rows 0-15  (gate logits)
    f32x4 acc1 = {0.f, 0.f, 0.f, 0.f};              // D rows 16-31 (noise logits)

#pragma unroll 16
    for (int s = 0; s < KSTEPS; ++s) {
        const float4 lo = *(const float4*)(xb + s * 32);
        const float4 hi = *(const float4*)(xb + s * 32 + 4);
        const bf16x8 a0 = *(const bf16x8*)(wb + (size_t)(s * 2 + 0) * 512);
        const bf16x8 a1 = *(const bf16x8*)(wb + (size_t)(s * 2 + 1) * 512);
        bf16x8 b;
        b[0] = f2bf(lo.x); b[1] = f2bf(lo.y); b[2] = f2bf(lo.z); b[3] = f2bf(lo.w);
        b[4] = f2bf(hi.x); b[5] = f2bf(hi.y); b[6] = f2bf(hi.z); b[7] = f2bf(hi.w);
        acc0 = __builtin_amdgcn_mfma_f32_16x16x32_bf16(a0, b, acc0, 0, 0, 0);
        acc1 = __builtin_amdgcn_mfma_f32_16x16x32_bf16(a1, b, acc1, 0, 0, 0);
    }

    // ---- epilogue: lane holds experts e = grp*4 + r for token tok ----
    const float4 nz4 = *(const float4*)(noise + (size_t)tok * NEXP + grp * 4);
    const float nzv[4] = {nz4.x, nz4.y, nz4.z, nz4.w};

    float lg[4];
#pragma unroll
    for (int r = 0; r < 4; ++r) {
        const float cl = acc0[r];
        const float nl = acc1[r];
        const float sp = fmaxf(nl, 0.0f) + log1pf(expf(-fabsf(nl)));
        lg[r] = cl + nzv[r] * sp * 0.01f;
    }

    float m = fmaxf(fmaxf(lg[0], lg[1]), fmaxf(lg[2], lg[3]));
    m = fmaxf(m, __shfl_xor(m, 16, 64));
    m = fmaxf(m, __shfl_xor(m, 32, 64));

    float p[4];
    float ssum = 0.0f;
#pragma unroll
    for (int r = 0; r < 4; ++r) { p[r] = expf(lg[r] - m); ssum += p[r]; }
    ssum += __shfl_xor(ssum, 16, 64);
    ssum += __shfl_xor(ssum, 32, 64);
    const float inv = 1.0f / ssum;

    float g[4];
#pragma unroll
    for (int r = 0; r < 4; ++r) g[r] = p[r] * inv;

    // local top-2 (tie -> lower index), butterfly merge across the 4 lanes
    float v1 = -1.0f, v2 = -1.0f;
    int   i1 = 0,     i2 = 0;
#pragma unroll
    for (int r = 0; r < 4; ++r) {
        const float ge = g[r];
        const int   e  = grp * 4 + r;
        if (ge > v1)      { v2 = v1; i2 = i1; v1 = ge; i1 = e; }
        else if (ge > v2) { v2 = ge; i2 = e; }
    }
#pragma unroll
    for (int off = 16; off <= 32; off <<= 1) {
        const float ov1 = __shfl_xor(v1, off, 64);
        const float ov2 = __shfl_xor(v2, off, 64);
        const int   oi1 = __shfl_xor(i1, off, 64);
        const int   oi2 = __shfl_xor(i2, off, 64);
        const bool aWins = (v1 > ov1) || (v1 == ov1 && i1 < oi1);
        float nv1, nv2; int ni1, ni2;
        if (aWins) {
            nv1 = v1; ni1 = i1;
            const bool bNext = (ov1 > v2) || (ov1 == v2 && oi1 < i2);
            nv2 = bNext ? ov1 : v2;  ni2 = bNext ? oi1 : i2;
        } else {
            nv1 = ov1; ni1 = oi1;
            const bool aNext = (v1 > ov2) || (v1 == ov2 && i1 < oi2);
            nv2 = aNext ? v1 : ov2;  ni2 = aNext ? i1 : oi2;
        }
        v1 = nv1; v2 = nv2; i1 = ni1; i2 = ni2;
    }
    if (grp == 0) {
        const float den = v1 + v2 + 1e-8f;
        out_gates[(size_t)tok * 2 + 0] = v1 / den;
        out_gates[(size_t)tok * 2 + 1] = v2 / den;
        out_idx[(size_t)tok * 2 + 0] = (float)i1;
        out_idx[(size_t)tok * 2 + 1] = (float)i2;
    }

    // load partials: sum g over the 16 tokens of this wave (butterfly over lane&15)
#pragma unroll
    for (int r = 0; r < 4; ++r) {
        float v = g[r];
        v += __shfl_xor(v, 1, 64);
        v += __shfl_xor(v, 2, 64);
        v += __shfl_xor(v, 4, 64);
        v += __shfl_xor(v, 8, 64);
        if ((lane & 15) == 0) atomicAdd(&blk_load[grp * 4 + r], v);
    }
    __syncthreads();
    if (tid < NEXP) partials[(size_t)blockIdx.x * NEXP + tid] = blk_load[tid];
}

__global__ __launch_bounds__(64) void reduce_load(
    const float* __restrict__ partials, float* __restrict__ out_load)
{
    const int lane = threadIdx.x;
    float loc[16];
#pragma unroll
    for (int e = 0; e < 16; ++e) loc[e] = 0.0f;
    for (int b = lane; b < NBLK; b += 64) {
        const float4* p = (const float4*)(partials + (size_t)b * 16);
#pragma unroll
        for (int j = 0; j < 4; ++j) {
            const float4 v = p[j];
            loc[j * 4 + 0] += v.x; loc[j * 4 + 1] += v.y;
            loc[j * 4 + 2] += v.z; loc[j * 4 + 3] += v.w;
        }
    }
#pragma unroll
    for (int e = 0; e < 16; ++e) {
        float v = loc[e];
#pragma unroll
        for (int off = 32; off; off >>= 1) v += __shfl_xor(v, off, 64);
        if (lane == 0) out_load[e] = v;
    }
}

extern "C" void kernel_launch(void* const* d_in, const int* in_sizes, int n_in,
                              void* d_out, int out_size, void* d_ws, size_t ws_size,
                              hipStream_t stream) {
    (void)in_sizes; (void)n_in; (void)ws_size; (void)out_size;
    const float* x     = (const float*)d_in[0];
    const float* noise = (const float*)d_in[1];
    const float* Wg    = (const float*)d_in[2];
    const float* Wn    = (const float*)d_in[3];

    float* out       = (float*)d_out;
    float* out_gates = out;
    float* out_idx   = out + (size_t)N_TOK * 2;
    float* out_load  = out + (size_t)N_TOK * 4;

    unsigned short* Wfrag = (unsigned short*)d_ws;                 // 64 KB
    float* partials = (float*)((char*)d_ws + 65536);               // NBLK*16 floats

    make_wfrag<<<128, 256, 0, stream>>>(Wg, Wn, Wfrag);            // 32768 elems
    router_mfma<<<NBLK, THREADS, 0, stream>>>(
        x, noise, Wfrag, out_gates, out_idx, partials);
    reduce_load<<<1, 64, 0, stream>>>(partials, out_load);
}